// Round 3
// baseline (370.293 us; speedup 1.0000x reference)
//
#include <hip/hip_runtime.h>

// Problem constants (from the reference): x is [K,N,M] fp32.
// Critical insight: softmax over a size-1 axis == 1.0 exactly, so
//   attention_map = ones([K,N])        (independent of all weights)
//   result[k,m]   = sum_n x[k,n,m]
// The entire gated-MLP branch is mathematically dead. This is a pure
// memory-bound N-axis reduction (256 MiB read) + constant fill.

#define KK 32
#define NN 8192
#define MM 256
#define NBLK 64              // N-chunks per k  -> grid = 32*64 = 2048 blocks
#define CHUNK (NN / NBLK)    // 128 rows of N per block
#define M4 (MM / 4)          // 64 float4 per row

// ---------------- phase 1: per-(k, n-chunk) partial sums + ones fill ----------
// grid = KK*NBLK blocks, 256 threads. Thread t: m4 = t&63 (float4 column),
// ns = t>>6 (one of 4 n-sublanes). Coalesced float4 loads: consecutive lanes
// read consecutive 16B -> 4 KB per block per iteration row-group.
__global__ __launch_bounds__(256) void partial_reduce_kernel(
    const float* __restrict__ x, float* __restrict__ ws,
    float* __restrict__ att_out) {
  const int bid = blockIdx.x;
  const int k   = bid >> 6;     // bid / NBLK
  const int nb  = bid & 63;     // bid % NBLK
  const int t   = threadIdx.x;
  const int m4  = t & 63;
  const int ns  = t >> 6;

  const float4* __restrict__ x4 =
      reinterpret_cast<const float4*>(x) +
      ((size_t)k * NN + (size_t)nb * CHUNK) * M4;

  // Two independent accumulators (n-sublane strides of 8) for deeper ILP.
  float4 acc0 = make_float4(0.f, 0.f, 0.f, 0.f);
  float4 acc1 = make_float4(0.f, 0.f, 0.f, 0.f);
#pragma unroll 4
  for (int n = ns; n < CHUNK; n += 8) {
    float4 v0 = x4[(size_t)n * M4 + m4];
    float4 v1 = x4[(size_t)(n + 4) * M4 + m4];
    acc0.x += v0.x; acc0.y += v0.y; acc0.z += v0.z; acc0.w += v0.w;
    acc1.x += v1.x; acc1.y += v1.y; acc1.z += v1.z; acc1.w += v1.w;
  }
  float4 acc;
  acc.x = acc0.x + acc1.x; acc.y = acc0.y + acc1.y;
  acc.z = acc0.z + acc1.z; acc.w = acc0.w + acc1.w;

  __shared__ float4 red[256];
  red[t] = acc;
  __syncthreads();

  if (t < 64) {  // wave 0: fold the 4 n-sublanes, store partial row
    float4 a = red[t], b = red[64 + t], c = red[128 + t], d = red[192 + t];
    float4 s;
    s.x = (a.x + b.x) + (c.x + d.x);
    s.y = (a.y + b.y) + (c.y + d.y);
    s.z = (a.z + b.z) + (c.z + d.z);
    s.w = (a.w + b.w) + (c.w + d.w);
    reinterpret_cast<float4*>(ws)[(size_t)bid * M4 + t] = s;
  }

  // wave 2 writes its slice of attention_map = 1.0:
  // 2048 blocks * 32 float4 = 65536 float4 = 262144 floats = K*N. Exact cover.
  if (t >= 128 && t < 160) {
    reinterpret_cast<float4*>(att_out)[(size_t)bid * 32 + (t - 128)] =
        make_float4(1.f, 1.f, 1.f, 1.f);
  }
}

// Atomic fallback variant (used only if d_ws is too small): accumulates
// straight into out (which is zeroed by hipMemsetAsync first).
__global__ __launch_bounds__(256) void partial_reduce_atomic_kernel(
    const float* __restrict__ x, float* __restrict__ out,
    float* __restrict__ att_out) {
  const int bid = blockIdx.x;
  const int k   = bid >> 6;
  const int nb  = bid & 63;
  const int t   = threadIdx.x;
  const int m4  = t & 63;
  const int ns  = t >> 6;

  const float4* __restrict__ x4 =
      reinterpret_cast<const float4*>(x) +
      ((size_t)k * NN + (size_t)nb * CHUNK) * M4;

  float4 acc = make_float4(0.f, 0.f, 0.f, 0.f);
#pragma unroll 4
  for (int n = ns; n < CHUNK; n += 4) {
    float4 v = x4[(size_t)n * M4 + m4];
    acc.x += v.x; acc.y += v.y; acc.z += v.z; acc.w += v.w;
  }

  __shared__ float4 red[256];
  red[t] = acc;
  __syncthreads();

  if (t < 64) {
    float4 a = red[t], b = red[64 + t], c = red[128 + t], d = red[192 + t];
    float* o = out + (size_t)k * MM + (size_t)t * 4;
    atomicAdd(o + 0, (a.x + b.x) + (c.x + d.x));
    atomicAdd(o + 1, (a.y + b.y) + (c.y + d.y));
    atomicAdd(o + 2, (a.z + b.z) + (c.z + d.z));
    atomicAdd(o + 3, (a.w + b.w) + (c.w + d.w));
  }

  if (t >= 128 && t < 160) {
    reinterpret_cast<float4*>(att_out)[(size_t)bid * 32 + (t - 128)] =
        make_float4(1.f, 1.f, 1.f, 1.f);
  }
}

// ---------------- phase 2: fold the NBLK partials per k ----------------------
// grid = KK blocks, 256 threads. ws layout: [K][NBLK][M] contiguous ->
// per-k slab is 64 KiB, reads coalesced (lane-fast over m4).
__global__ __launch_bounds__(256) void final_reduce_kernel(
    const float* __restrict__ ws, float* __restrict__ out) {
  const int k  = blockIdx.x;
  const int t  = threadIdx.x;
  const int m4 = t & 63;
  const int ns = t >> 6;

  const float4* __restrict__ w4 =
      reinterpret_cast<const float4*>(ws) + (size_t)k * NBLK * M4;

  float4 acc = make_float4(0.f, 0.f, 0.f, 0.f);
#pragma unroll
  for (int nb = ns; nb < NBLK; nb += 4) {
    float4 v = w4[(size_t)nb * M4 + m4];
    acc.x += v.x; acc.y += v.y; acc.z += v.z; acc.w += v.w;
  }

  __shared__ float4 red[256];
  red[t] = acc;
  __syncthreads();

  if (t < 64) {
    float4 a = red[t], b = red[64 + t], c = red[128 + t], d = red[192 + t];
    float4 s;
    s.x = (a.x + b.x) + (c.x + d.x);
    s.y = (a.y + b.y) + (c.y + d.y);
    s.z = (a.z + b.z) + (c.z + d.z);
    s.w = (a.w + b.w) + (c.w + d.w);
    reinterpret_cast<float4*>(out)[(size_t)k * M4 + t] = s;
  }
}

extern "C" void kernel_launch(void* const* d_in, const int* in_sizes, int n_in,
                              void* d_out, int out_size, void* d_ws, size_t ws_size,
                              hipStream_t stream) {
  const float* x = reinterpret_cast<const float*>(d_in[0]);
  // d_out: [ result (K*M = 8192 floats) | attention_map (K*N = 262144 floats) ]
  float* out_result = reinterpret_cast<float*>(d_out);
  float* out_attmap = out_result + (size_t)KK * MM;

  const size_t ws_needed = (size_t)KK * NBLK * MM * sizeof(float);  // 2 MiB

  if (ws_size >= ws_needed) {
    float* partials = reinterpret_cast<float*>(d_ws);
    partial_reduce_kernel<<<KK * NBLK, 256, 0, stream>>>(x, partials, out_attmap);
    final_reduce_kernel<<<KK, 256, 0, stream>>>(partials, out_result);
  } else {
    // Fallback: zero result region, accumulate with device-scope atomics.
    hipMemsetAsync(out_result, 0, (size_t)KK * MM * sizeof(float), stream);
    partial_reduce_atomic_kernel<<<KK * NBLK, 256, 0, stream>>>(x, out_result, out_attmap);
  }
}

// Round 4
// 367.176 us; speedup vs baseline: 1.0085x; 1.0085x over previous
//
#include <hip/hip_runtime.h>

// x is [K,N,M] fp32. softmax over a size-1 axis == 1.0 exactly, so
//   attention_map = ones([K,N])   (independent of all weights)
//   result[k,m]   = sum_n x[k,n,m]
// Pure memory-bound N-axis reduction (256 MiB read) + constant fill.
//
// Round-4 structure: ONE reduction kernel (atomics over L2 fold the 64
// per-k partial blocks) + a 32 KB async memset to zero the poisoned output.
// This removes the former final_reduce dispatch (~6-8 us, 32-block
// latency-bound) and the 2 MiB workspace round-trip.

#define KK 32
#define NN 8192
#define MM 256
#define NBLK 64              // N-chunks per k  -> grid = 32*64 = 2048 blocks
#define CHUNK (NN / NBLK)    // 128 rows of N per block
#define M4 (MM / 4)          // 64 float4 per row

// grid = KK*NBLK blocks, 256 threads. Thread t: m4 = t&63 (float4 column),
// ns = t>>6 (one of 4 n-sublanes). Consecutive lanes read consecutive 16B.
__global__ __launch_bounds__(256) void reduce_kernel(
    const float* __restrict__ x, float* __restrict__ out,
    float* __restrict__ att_out) {
  const int bid = blockIdx.x;
  const int k   = bid >> 6;     // bid / NBLK
  const int nb  = bid & 63;     // bid % NBLK
  const int t   = threadIdx.x;
  const int m4  = t & 63;
  const int ns  = t >> 6;

  // attention_map = 1.0 fill: 2048 blocks * 32 float4 = 262144 floats = K*N.
  // Issued first so the stores drain under the load loop.
  if (t >= 128 && t < 160) {
    reinterpret_cast<float4*>(att_out)[(size_t)bid * 32 + (t - 128)] =
        make_float4(1.f, 1.f, 1.f, 1.f);
  }

  const float4* __restrict__ x4 =
      reinterpret_cast<const float4*>(x) +
      ((size_t)k * NN + (size_t)nb * CHUNK) * M4;

  // Two independent accumulators (n strides of 8) for deeper ILP.
  float4 acc0 = make_float4(0.f, 0.f, 0.f, 0.f);
  float4 acc1 = make_float4(0.f, 0.f, 0.f, 0.f);
#pragma unroll 4
  for (int n = ns; n < CHUNK; n += 8) {
    float4 v0 = x4[(size_t)n * M4 + m4];
    float4 v1 = x4[(size_t)(n + 4) * M4 + m4];
    acc0.x += v0.x; acc0.y += v0.y; acc0.z += v0.z; acc0.w += v0.w;
    acc1.x += v1.x; acc1.y += v1.y; acc1.z += v1.z; acc1.w += v1.w;
  }
  float4 acc;
  acc.x = acc0.x + acc1.x; acc.y = acc0.y + acc1.y;
  acc.z = acc0.z + acc1.z; acc.w = acc0.w + acc1.w;

  __shared__ float4 red[256];
  red[t] = acc;
  __syncthreads();

  // Fold 4 n-sublanes and emit ONE atomicAdd per thread (256 threads cover
  // the 256 m-elements of this k). LDS re-read as floats: index g*256 + t
  // for group g -> consecutive t hit consecutive banks, conflict-free.
  const float* r = reinterpret_cast<const float*>(red);
  const int m4r = t >> 2;
  const int c   = t & 3;
  float s = (r[(0 * 64 + m4r) * 4 + c] + r[(1 * 64 + m4r) * 4 + c]) +
            (r[(2 * 64 + m4r) * 4 + c] + r[(3 * 64 + m4r) * 4 + c]);
  atomicAdd(&out[(size_t)k * MM + t], s);  // 64 adds per address, via L2
}

extern "C" void kernel_launch(void* const* d_in, const int* in_sizes, int n_in,
                              void* d_out, int out_size, void* d_ws, size_t ws_size,
                              hipStream_t stream) {
  const float* x = reinterpret_cast<const float*>(d_in[0]);
  // d_out: [ result (K*M = 8192 floats) | attention_map (K*N = 262144 floats) ]
  float* out_result = reinterpret_cast<float*>(d_out);
  float* out_attmap = out_result + (size_t)KK * MM;

  // d_out is poisoned 0xAA before every timed launch: zero the accumulator
  // region (32 KB, ~2 us) before the atomic reduction.
  hipMemsetAsync(out_result, 0, (size_t)KK * MM * sizeof(float), stream);
  reduce_kernel<<<KK * NBLK, 256, 0, stream>>>(x, out_result, out_attmap);
}